// Round 9
// baseline (910.611 us; speedup 1.0000x reference)
//
#include <hip/hip_runtime.h>

#define TLEN  1024
#define HN    64
#define LOG2E 1.4426950408889634f

// clang builtins (cvt_pkrtz / fdot2) take __fp16 vectors, not _Float16 (R7).
typedef __fp16 half2v __attribute__((ext_vector_type(2)));

// One wave per batch element; 1024 blocks x 64 thr = 1 wave/SIMD exactly.
// Lane g owns hidden unit g's four gate rows as packed f16 pairs {w[j],
// w[j+32]} -- but stored in 128 AGPRs via explicit v_accvgpr_write (R2-R8:
// the allocator refuses >~50 cross-loop VGPRs and spills to scratch; R8's
// VGPR=84 + 41ms scratch outlier proved it again). a-class has 256 regs,
// 128 used, no pressure -> structurally spill-proof. Loop reads them back
// with v_accvgpr_read (volatile: blocks loop-invariant hoisting that would
// recreate the VGPR live set). v_dot2_f32_f16 = 2 MACs/instr, fp32 acc.
// h broadcast: hp = cvt_pkrtz(h, shfl_down(h,32)); 32 readlanes feed 128
// dot2. No barriers, no LDS in the recurrence. log2e pre-folded (2*log2e
// for the tanh gate). FC: ring[64][65] + coalesced store every 64 steps.

#define FOR32(X) \
    X(0) X(1) X(2) X(3) X(4) X(5) X(6) X(7) \
    X(8) X(9) X(10) X(11) X(12) X(13) X(14) X(15) \
    X(16) X(17) X(18) X(19) X(20) X(21) X(22) X(23) \
    X(24) X(25) X(26) X(27) X(28) X(29) X(30) X(31)

__global__ __launch_bounds__(64, 1)
void lstm_agpr(const float* __restrict__ x,      // [B, T, 4]
               const float* __restrict__ W_ih,   // [256, 4]
               const float* __restrict__ W_hh,   // [256, 64]
               const float* __restrict__ b_ih,   // [256]
               const float* __restrict__ b_hh,   // [256]
               const float* __restrict__ W_fc,   // [1, 64]
               const float* __restrict__ b_fc,   // [1]
               float* __restrict__ out)          // [B, T]
{
    const int b = blockIdx.x;
    const int g = threadIdx.x;   // hidden unit 0..63

    __shared__ float ring[64][65];   // FC partials, stride-65: conflict-free

    const float* wr_i = W_hh + (0 * HN + g) * HN;
    const float* wr_f = W_hh + (1 * HN + g) * HN;
    const float* wr_g = W_hh + (2 * HN + g) * HN;
    const float* wr_o = W_hh + (3 * HN + g) * HN;

    // ---- 128 AGPR-resident packed weight pairs ----
#define DECL(j) int awi##j, awf##j, awg##j, awo##j;
    FOR32(DECL)
#undef DECL

#define PK(lo, hi) __builtin_bit_cast(int, __builtin_amdgcn_cvt_pkrtz((lo), (hi)))
#define LOADW(j) { \
    int ti = PK(wr_i[j] * LOG2E,          wr_i[(j) + 32] * LOG2E); \
    int tf = PK(wr_f[j] * LOG2E,          wr_f[(j) + 32] * LOG2E); \
    int tg = PK(wr_g[j] * (2.0f * LOG2E), wr_g[(j) + 32] * (2.0f * LOG2E)); \
    int to = PK(wr_o[j] * LOG2E,          wr_o[(j) + 32] * LOG2E); \
    asm volatile("v_accvgpr_write_b32 %0, %1" : "=a"(awi##j) : "v"(ti)); \
    asm volatile("v_accvgpr_write_b32 %0, %1" : "=a"(awf##j) : "v"(tf)); \
    asm volatile("v_accvgpr_write_b32 %0, %1" : "=a"(awg##j) : "v"(tg)); \
    asm volatile("v_accvgpr_write_b32 %0, %1" : "=a"(awo##j) : "v"(to)); \
    __builtin_amdgcn_sched_barrier(0); /* cap prologue pressure: no scratch */ }
    FOR32(LOADW)
#undef LOADW
#undef PK

    // x-weights as f16 pairs (pre-scaled): 2 half2 per gate, plain VGPRs
    half2v wip0 = __builtin_amdgcn_cvt_pkrtz(W_ih[(0 * HN + g) * 4 + 0] * LOG2E,
                                             W_ih[(0 * HN + g) * 4 + 1] * LOG2E);
    half2v wip1 = __builtin_amdgcn_cvt_pkrtz(W_ih[(0 * HN + g) * 4 + 2] * LOG2E,
                                             W_ih[(0 * HN + g) * 4 + 3] * LOG2E);
    half2v wfp0 = __builtin_amdgcn_cvt_pkrtz(W_ih[(1 * HN + g) * 4 + 0] * LOG2E,
                                             W_ih[(1 * HN + g) * 4 + 1] * LOG2E);
    half2v wfp1 = __builtin_amdgcn_cvt_pkrtz(W_ih[(1 * HN + g) * 4 + 2] * LOG2E,
                                             W_ih[(1 * HN + g) * 4 + 3] * LOG2E);
    half2v wgp0 = __builtin_amdgcn_cvt_pkrtz(W_ih[(2 * HN + g) * 4 + 0] * 2.0f * LOG2E,
                                             W_ih[(2 * HN + g) * 4 + 1] * 2.0f * LOG2E);
    half2v wgp1 = __builtin_amdgcn_cvt_pkrtz(W_ih[(2 * HN + g) * 4 + 2] * 2.0f * LOG2E,
                                             W_ih[(2 * HN + g) * 4 + 3] * 2.0f * LOG2E);
    half2v wop0 = __builtin_amdgcn_cvt_pkrtz(W_ih[(3 * HN + g) * 4 + 0] * LOG2E,
                                             W_ih[(3 * HN + g) * 4 + 1] * LOG2E);
    half2v wop1 = __builtin_amdgcn_cvt_pkrtz(W_ih[(3 * HN + g) * 4 + 2] * LOG2E,
                                             W_ih[(3 * HN + g) * 4 + 3] * LOG2E);

    const float bias_i = (b_ih[0 * HN + g] + b_hh[0 * HN + g]) * LOG2E;
    const float bias_f = (b_ih[1 * HN + g] + b_hh[1 * HN + g]) * LOG2E;
    const float bias_g = (b_ih[2 * HN + g] + b_hh[2 * HN + g]) * (2.0f * LOG2E);
    const float bias_o = (b_ih[3 * HN + g] + b_hh[3 * HN + g]) * LOG2E;
    const float wfc = W_fc[g];
    const float bfc = b_fc[0];

    const float* xb = x   + (size_t)b * TLEN * 4;
    float*       ob = out + (size_t)b * TLEN;

    float h = 0.0f, c = 0.0f;
    int hp = 0;   // packed h pair {h[j], h[j+32]} per lane (h starts at 0)

    float4 x0 = *(const float4*)(xb);
    half2v xp0 = __builtin_amdgcn_cvt_pkrtz(x0.x, x0.y);
    half2v xp1 = __builtin_amdgcn_cvt_pkrtz(x0.z, x0.w);

    for (int t = 0; t < TLEN; ++t) {
        int tn = t + 1; if (tn >= TLEN) tn = TLEN - 1;
        float4 xn = *(const float4*)(xb + (size_t)tn * 4);   // prefetch

        // ---- gate accumulators: bias + x.W_ih (2 dot2 each) ----
        float ai = __builtin_amdgcn_fdot2(wip0, xp0, bias_i, false);
        float af = __builtin_amdgcn_fdot2(wfp0, xp0, bias_f, false);
        float ag = __builtin_amdgcn_fdot2(wgp0, xp0, bias_g, false);
        float ao = __builtin_amdgcn_fdot2(wop0, xp0, bias_o, false);
        ai = __builtin_amdgcn_fdot2(wip1, xp1, ai, false);
        af = __builtin_amdgcn_fdot2(wfp1, xp1, af, false);
        ag = __builtin_amdgcn_fdot2(wgp1, xp1, ag, false);
        ao = __builtin_amdgcn_fdot2(wop1, xp1, ao, false);

        // ---- hh matvec: 32 x (readlane + 4 agpr reads + 4 dot2) ----
#define MAC(j) { \
        int hj = __builtin_amdgcn_readlane(hp, j); \
        half2v hh = __builtin_bit_cast(half2v, hj); \
        int vi, vf, vg, vo; \
        asm volatile("v_accvgpr_read_b32 %0, %1" : "=v"(vi) : "a"(awi##j)); \
        asm volatile("v_accvgpr_read_b32 %0, %1" : "=v"(vf) : "a"(awf##j)); \
        asm volatile("v_accvgpr_read_b32 %0, %1" : "=v"(vg) : "a"(awg##j)); \
        asm volatile("v_accvgpr_read_b32 %0, %1" : "=v"(vo) : "a"(awo##j)); \
        ai = __builtin_amdgcn_fdot2(__builtin_bit_cast(half2v, vi), hh, ai, false); \
        af = __builtin_amdgcn_fdot2(__builtin_bit_cast(half2v, vf), hh, af, false); \
        ag = __builtin_amdgcn_fdot2(__builtin_bit_cast(half2v, vg), hh, ag, false); \
        ao = __builtin_amdgcn_fdot2(__builtin_bit_cast(half2v, vo), hh, ao, false); }
        FOR32(MAC)
#undef MAC

        // ---- activations (pre-scaled): sigmoid/tanh via exp2+rcp ----
        float si = __builtin_amdgcn_rcpf(1.0f + __builtin_amdgcn_exp2f(-ai));
        float sf = __builtin_amdgcn_rcpf(1.0f + __builtin_amdgcn_exp2f(-af));
        float tg = 1.0f - 2.0f * __builtin_amdgcn_rcpf(
                                     1.0f + __builtin_amdgcn_exp2f(ag));
        float so = __builtin_amdgcn_rcpf(1.0f + __builtin_amdgcn_exp2f(-ao));

        c = sf * c + si * tg;
        float th = 1.0f - 2.0f * __builtin_amdgcn_rcpf(
                       1.0f + __builtin_amdgcn_exp2f(c * (2.0f * LOG2E)));
        h = so * th;

        // repack h pairs for next step's readlane broadcast
        float h_hi = __shfl_down(h, 32, 64);
        hp = __builtin_bit_cast(int, __builtin_amdgcn_cvt_pkrtz(h, h_hi));

        // repack next x
        xp0 = __builtin_amdgcn_cvt_pkrtz(xn.x, xn.y);
        xp1 = __builtin_amdgcn_cvt_pkrtz(xn.z, xn.w);

        // ---- FC ring + periodic coalesced store ----
        ring[t & 63][g] = h * wfc;
        if ((t & 63) == 63) {
            __syncthreads();   // single wave: just orders LDS w->r
            float s0 = 0.f, s1 = 0.f, s2 = 0.f, s3 = 0.f;
#pragma unroll
            for (int k = 0; k < HN; k += 4) {
                s0 += ring[g][k];
                s1 += ring[g][k + 1];
                s2 += ring[g][k + 2];
                s3 += ring[g][k + 3];
            }
            ob[(t - 63) + g] = (s0 + s1) + (s2 + s3) + bfc;
        }
    }
}

extern "C" void kernel_launch(void* const* d_in, const int* in_sizes, int n_in,
                              void* d_out, int out_size, void* d_ws, size_t ws_size,
                              hipStream_t stream) {
    const float* x    = (const float*)d_in[0];
    const float* W_ih = (const float*)d_in[1];
    const float* W_hh = (const float*)d_in[2];
    const float* b_ih = (const float*)d_in[3];
    const float* b_hh = (const float*)d_in[4];
    const float* W_fc = (const float*)d_in[5];
    const float* b_fc = (const float*)d_in[6];
    float* out = (float*)d_out;

    const int B = in_sizes[0] / (TLEN * 4);   // 1024
    lstm_agpr<<<dim3(B), dim3(64), 0, stream>>>(
        x, W_ih, W_hh, b_ih, b_hh, W_fc, b_fc, out);
}